// Round 19
// baseline (185.298 us; speedup 1.0000x reference)
//
#include <hip/hip_runtime.h>

typedef unsigned short u16;
typedef __attribute__((ext_vector_type(8))) short short8;   // 8 x bf16 (4 VGPRs)
typedef __attribute__((ext_vector_type(4))) short short4v;
typedef __attribute__((ext_vector_type(4))) float f32x4;

#define B_  4
#define T_  2048
#define D_  1024
#define H_  16
#define HS_ 64
#define M_    (B_ * T_)        /* 8192 */
#define NQKV_ (H_ * 3 * HS_)   /* 3072 */
#define NTILE_ (T_ / 64)       /* 32 */
#define LOG2E_ 1.44269504088896340736f

__device__ __forceinline__ u16 f2bf(float f) {
  union { float f; unsigned u; } v; v.f = f;
  unsigned u = v.u;
  return (u16)((u + 0x7FFFu + ((u >> 16) & 1u)) >> 16);  // RNE
}
__device__ __forceinline__ float bf2f(u16 h) {
  union { unsigned u; float f; } v; v.u = ((unsigned)h) << 16; return v.f;
}
__device__ __forceinline__ unsigned pkbf(float lo, float hi) {
  unsigned r;
  asm("v_cvt_pk_bf16_f32 %0, %1, %2" : "=v"(r) : "v"(lo), "v"(hi));
  return r;
}
__device__ __forceinline__ float exp2fast(float x) {  // scores bounded (|x|<~8): no fixup needed
  float r;
  asm("v_exp_f32 %0, %1" : "=v"(r) : "v"(x));
  return r;
}
__device__ __forceinline__ void gload16(const u16* g, u16* l) {
  __builtin_amdgcn_global_load_lds(
      (const __attribute__((address_space(1))) void*)g,
      (__attribute__((address_space(3))) void*)l, 16, 0, 0);
}

// ---------------- convert x (fp32) -> bf16, 8 elems/thread ----------------
__global__ void k_cvt_x(const float* __restrict__ x, u16* __restrict__ o, int n8) {
  int i = blockIdx.x * 256 + threadIdx.x;
  if (i < n8) {
    float4 v0 = ((const float4*)x)[i * 2];
    float4 v1 = ((const float4*)x)[i * 2 + 1];
    short8 d;
    d[0] = (short)f2bf(v0.x); d[1] = (short)f2bf(v0.y);
    d[2] = (short)f2bf(v0.z); d[3] = (short)f2bf(v0.w);
    d[4] = (short)f2bf(v1.x); d[5] = (short)f2bf(v1.y);
    d[6] = (short)f2bf(v1.z); d[7] = (short)f2bf(v1.w);
    ((short8*)o)[i] = d;
  }
}

// ------- transpose+convert: in fp32 [R][C] (+h*sIn) -> out bf16 [C][R] (+h*sOut) -------
__global__ void k_transpose_cvt(const float* __restrict__ in, u16* __restrict__ out,
                                int R, int C, long sIn, long sOut) {
  __shared__ float tile[32][33];
  int h = blockIdx.z;
  const float* src = in + (long)h * sIn;
  u16* dst = out + (long)h * sOut;
  int r0 = blockIdx.y * 32, c0 = blockIdx.x * 32;
  int tx = threadIdx.x, ty = threadIdx.y;  // 32 x 8
  #pragma unroll
  for (int i = 0; i < 32; i += 8) {
    int r = r0 + ty + i, c = c0 + tx;
    tile[ty + i][tx] = (r < R && c < C) ? src[(long)r * C + c] : 0.f;
  }
  __syncthreads();
  #pragma unroll
  for (int i = 0; i < 32; i += 8) {
    int c = c0 + ty + i, r = r0 + tx;
    if (c < C && r < R) dst[(long)c * R + r] = f2bf(tile[tx][ty + i]);
  }
}

// ---------------- GEMM: C[M][N] = A[M][K] @ Bt[N][K]^T (bf16 in, fp32 acc) ----------------
// r16 proven structure (unchanged): 2D grid (mt fast; round-robin pins mt%8 per XCD).
// Double-buffered issue-before-compute staging, ONE __syncthreads() per K-step.
// BK=64, LDS [128][8 chunks] with chunk^=(row&7) XOR swizzle on BOTH source and reads.
template<int MODE>
__global__ __launch_bounds__(256) void k_gemm(
    const u16* __restrict__ A, const u16* __restrict__ Bt,
    u16* __restrict__ Oq, u16* __restrict__ Ok, u16* __restrict__ Ov,
    float* __restrict__ Of, int K) {
  __shared__ __align__(16) u16 smem[32768];   // [buf]*16384: As 8192 | Bs 8192 ; Cs aliases
  int mt = blockIdx.x, nt = blockIdx.y;
  int tid = threadIdx.x;
  int wid = tid >> 6, lane = tid & 63;
  int lr = lane & 15, lg = lane >> 4;
  int mw = (wid >> 1) * 64, nw = (wid & 1) * 64;
  const u16* srcA[4]; const u16* srcB[4];
  int dstOff[4];
  #pragma unroll
  for (int l = 0; l < 4; l++) {
    int c = l * 256 + wid * 64 + lane;
    int r = c >> 3, q = c & 7;
    int qs = q ^ (r & 7);
    srcA[l] = A  + (long)(mt * 128 + r) * K + qs * 8;
    srcB[l] = Bt + (long)(nt * 128 + r) * K + qs * 8;
    dstOff[l] = (l * 256 + wid * 64) * 8;     // wave-uniform base (lane*16B implicit)
  }
  const int rsw = (lr & 7);                   // row&7 for all frag rows (row ≡ lr mod 16)
  f32x4 acc[4][4] = {};
  const int nIter = K / 64;

#define STAGE_G(bb, k0) do {                       \
    u16* ab_ = smem + (bb) * 16384;                \
    gload16(srcA[0] + (k0), ab_ + dstOff[0]);      \
    gload16(srcA[1] + (k0), ab_ + dstOff[1]);      \
    gload16(srcA[2] + (k0), ab_ + dstOff[2]);      \
    gload16(srcA[3] + (k0), ab_ + dstOff[3]);      \
    u16* bb_ = ab_ + 8192;                         \
    gload16(srcB[0] + (k0), bb_ + dstOff[0]);      \
    gload16(srcB[1] + (k0), bb_ + dstOff[1]);      \
    gload16(srcB[2] + (k0), bb_ + dstOff[2]);      \
    gload16(srcB[3] + (k0), bb_ + dstOff[3]); } while (0)

  STAGE_G(0, 0);
  __syncthreads();
  for (int t = 0; t < nIter; t++) {
    int cur = t & 1;
    if (t + 1 < nIter) STAGE_G(cur ^ 1, (t + 1) * 64);   // prefetch hidden under compute
    const u16* As = smem + cur * 16384;
    const u16* Bs = As + 8192;
    #pragma unroll
    for (int kk = 0; kk < 2; kk++) {
      const int fc = ((kk * 4 + lg) ^ rsw) << 3;
      short8 af[4], bf[4];
      #pragma unroll
      for (int i = 0; i < 4; i++)
        af[i] = *(const short8*)(As + (mw + i * 16 + lr) * 64 + fc);
      #pragma unroll
      for (int i = 0; i < 4; i++)
        bf[i] = *(const short8*)(Bs + (nw + i * 16 + lr) * 64 + fc);
      #pragma unroll
      for (int i = 0; i < 4; i++)
        #pragma unroll
        for (int j = 0; j < 4; j++)
          acc[i][j] = __builtin_amdgcn_mfma_f32_16x16x32_bf16(af[i], bf[j], acc[i][j], 0, 0, 0);
    }
    __syncthreads();   // drains prefetch vmcnt (covered by compute); guards buffer reuse
  }
#undef STAGE_G

  if constexpr (MODE == 0) {
    // bounce through LDS (Cs aliases smem), then coalesced 16B stores
    u16* Cs = smem;
    #pragma unroll
    for (int j = 0; j < 4; j++) {
      int fbase = (nt * 128 + nw + j * 16) % 192;          // wave-uniform, multiple of 16
      float sc = (fbase < 64) ? (0.03125f * LOG2E_) : 1.0f;  // Q gets C^-0.5 * log2e
      #pragma unroll
      for (int i = 0; i < 4; i++) {
        int row = mw + i * 16 + lg * 4;
        int col = nw + j * 16 + lr;
        #pragma unroll
        for (int r = 0; r < 4; r++)
          Cs[(row + r) * 128 + col] = f2bf(acc[i][j][r] * sc);
      }
    }
    __syncthreads();
    #pragma unroll
    for (int p5 = 0; p5 < 8; p5++) {
      int idx = p5 * 2048 + tid * 8;
      int row = idx >> 7, col = idx & 127;
      short8 v = *(const short8*)(Cs + row * 128 + col);
      int m = mt * 128 + row;
      int n0 = nt * 128 + col;
      int b = m >> 11, t = m & (T_ - 1);
      int h = n0 / 192, f = n0 % 192;
      long o = (((long)(b * H_ + h)) * T_ + t) * HS_;
      u16* dst = (f < 64) ? (Oq + o + f) : (f < 128) ? (Ok + o + f - 64) : (Ov + o + f - 128);
      *(short8*)dst = v;
    }
  } else {
    #pragma unroll
    for (int i = 0; i < 4; i++) {
      #pragma unroll
      for (int j = 0; j < 4; j++) {
        int mbase = mt * 128 + mw + i * 16 + lg * 4;
        int n     = nt * 128 + nw + j * 16 + lr;
        #pragma unroll
        for (int r = 0; r < 4; r++)
          Of[(long)(mbase + r) * D_ + n] = acc[i][j][r];
      }
    }
  }
}

// -------- V [bh][T][64] -> slot-permuted tiles Vp[bh][jt][d][pos] + per-tile column sums --------
// pos(s) within a 64-tile: s = 16c + 4lg + r  ->  pos = lg*16 + c*4 + r
__global__ void k_transpose_v(const u16* __restrict__ V, u16* __restrict__ Vp,
                              float* __restrict__ Partial) {
  __shared__ u16 tile[64][65];
  __shared__ float psum[4][64];
  int bh = blockIdx.z;
  int jt = blockIdx.x;          // tile index
  int t0 = jt * 64;
  int tx = threadIdx.x & 63, ty = threadIdx.x >> 6;
  const u16* src = V + (long)bh * T_ * HS_;
  u16* dtile = Vp + (((long)bh * NTILE_) + jt) * 64 * 64;
  #pragma unroll
  for (int i = 0; i < 64; i += 4)
    tile[ty + i][tx] = src[(long)(t0 + ty + i) * HS_ + tx];
  __syncthreads();
  int pos = ((tx >> 2) & 3) * 16 + ((tx >> 4) & 3) * 4 + (tx & 3);
  #pragma unroll
  for (int i = 0; i < 64; i += 4)
    dtile[(ty + i) * 64 + pos] = tile[tx][ty + i];
  // per-tile column sums: thread (ty,tx) sums 16 rows of dim tx
  float s = 0.f;
  #pragma unroll
  for (int i = 0; i < 16; i++)
    s += bf2f(tile[ty * 16 + i][tx]);
  psum[ty][tx] = s;
  __syncthreads();
  if (threadIdx.x < 64)
    Partial[((long)bh * NTILE_ + jt) * HS_ + threadIdx.x] =
        psum[0][threadIdx.x] + psum[1][threadIdx.x] + psum[2][threadIdx.x] + psum[3][threadIdx.x];
}

// -------- suffix scan over tile sums: Suf[bh][j][d] = sum_{jt >= j} Partial[bh][jt][d] --------
__global__ void k_vscan(const float* __restrict__ Partial, float* __restrict__ Suf) {
  int bh = blockIdx.x;
  int d = threadIdx.x;
  const float* Pb = Partial + (long)bh * NTILE_ * HS_;
  float* Sb = Suf + (long)bh * (NTILE_ + 1) * HS_;
  float acc = 0.f;
  Sb[NTILE_ * HS_ + d] = 0.f;
  for (int j = NTILE_ - 1; j >= 0; j--) {
    acc += Pb[j * HS_ + d];
    Sb[j * HS_ + d] = acc;
  }
}

// ---------------- fused attention: job-table grid for load balance ----------------
// 11 jobs per bh: jobs 0..5 = q-SPLIT heavy supertiles (st=7,7,6,6,5,5; h=job&1; 128 q rows,
// 16 q/wave, gcount=1; h=0 half also has a SHORTER k-range blkJ=4st+2h+1); jobs 6..10 =
// unsplit st=4..0 (256 q, 32 q/wave, gcount=2). 704 blocks > 512 slots (2/CU) -> hardware
// backfill; heavy jobs dispatch first. No-max softmax makes q-splitting merge-free.
// Same proven dbuf gload_lds protocol, ones-MFMA denominator, XOR swizzle, suffix correction.
__global__ __launch_bounds__(512, 2) void k_attn(
    const u16* __restrict__ Q, const u16* __restrict__ Kc,
    const u16* __restrict__ Vp, const float* __restrict__ Suf,
    u16* __restrict__ Mha) {
  __shared__ __align__(16) u16 Ks[2][64 * 64];
  __shared__ __align__(16) u16 Vs[2][64 * 64];
  int bh = blockIdx.x;
  int job = blockIdx.y;
  int b = bh >> 4, h = bh & 15;
  int tid = threadIdx.x, wid = tid >> 6, lane = tid & 63;
  int lr = lane & 15, lg = lane >> 4;
  int st, gcount, q0w, myJ, blkJ;
  if (job < 6) {               // q-split heavy halves (st = 7,6,5), 128 q rows
    st = 7 - (job >> 1);
    int hh = job & 1;
    gcount = 1;
    q0w = st * 256 + hh * 128 + wid * 16;
    myJ = 4 * st + 2 * hh + (wid >> 2);
    blkJ = 4 * st + 2 * hh + 1;
  } else {                     // unsplit (st = 4..0), 256 q rows
    st = 10 - job;
    gcount = 2;
    q0w = st * 256 + wid * 32;
    myJ = 4 * st + (wid >> 1);
    blkJ = 4 * st + 3;
  }
  const u16* Qb = Q  + (long)bh * T_ * HS_;
  const u16* Kb = Kc + (long)bh * T_ * HS_;
  const u16* Vb = Vp + (long)bh * T_ * HS_;   // [32 tiles][64 d][64 pos]
  union U8 { unsigned u[4]; short8 s; };
  const short8 vone = { (short)0x3F80, (short)0x3F80, (short)0x3F80, (short)0x3F80,
                        (short)0x3F80, (short)0x3F80, (short)0x3F80, (short)0x3F80 };
  // staging source (per-lane, inverse-swizzled 16B chunk), tile-relative; 512 chunks = 512 thr
  int srow = tid >> 3;                          // 0..63
  int schunk = (tid & 7) ^ (srow & 7);
  const u16* kSrc = Kb + srow * 64 + schunk * 8;
  const u16* vSrc = Vb + srow * 64 + schunk * 8;
  const int r7 = lr & 7;                        // row&7 for all frag rows (row ≡ lr mod 16)
  const int kc0 = (lg ^ r7) << 3, kc1 = ((4 + lg) ^ r7) << 3;
  const int vc0 = ((2 * lg) ^ r7) << 3, vc1 = ((2 * lg + 1) ^ r7) << 3;

  short8 qf[2][2];
  #pragma unroll
  for (int g = 0; g < 2; g++) {
    if (g >= gcount) continue;
    const u16* qp = Qb + (long)(q0w + g * 16 + lr) * HS_;
    qf[g][0] = *(const short8*)(qp + lg * 8);
    qf[g][1] = *(const short8*)(qp + 32 + lg * 8);
  }
  f32x4 accO[2][4] = {};                    // [group][fd]; O[q=lg*4+r][d=fd*16+lr]
  f32x4 accL[2] = {};                       // denominator rows (ones-MFMA)
  // prologue: stage tile 0 into buf 0 (1 K-chunk + 1 V-chunk per thread)
  gload16(kSrc, &Ks[0][wid * 512]);
  gload16(vSrc, &Vs[0][wid * 512]);
  __syncthreads();
  for (int jt = 0; jt <= blkJ; jt++) {
    int cur = jt & 1;
    if (jt < blkJ) {           // prefetch next tile into other buffer
      long off = (long)(jt + 1) * 4096;
      gload16(kSrc + off, &Ks[cur ^ 1][wid * 512]);
      gload16(vSrc + off, &Vs[cur ^ 1][wid * 512]);
    }
    if (jt <= myJ) {
      int j0 = jt * 64;
      const bool diag = (jt == myJ);
      const u16* Kl = Ks[cur];
      const u16* Vl = Vs[cur];
      // S^T = K Q^T : lane holds S[q=lr][s = j0 + fn*16 + lg*4 + r] per group
      f32x4 s4[2][4];
      #pragma unroll
      for (int fn = 0; fn < 4; fn++) {
        const u16* krow = Kl + (fn * 16 + lr) * 64;
        short8 kb0 = *(const short8*)(krow + kc0);
        short8 kb1 = *(const short8*)(krow + kc1);
        #pragma unroll
        for (int g = 0; g < 2; g++) {
          if (g >= gcount) continue;
          f32x4 z = {};
          z = __builtin_amdgcn_mfma_f32_16x16x32_bf16(kb0, qf[g][0], z, 0, 0, 0);
          z = __builtin_amdgcn_mfma_f32_16x16x32_bf16(kb1, qf[g][1], z, 0, 0, 0);
          s4[g][fn] = z;
        }
      }
      // no-max softmax + pack; denominator via ones-MFMA (lands in accO row layout)
      U8 pa[2][2];
      #pragma unroll
      for (int g = 0; g < 2; g++) {
        if (g >= gcount) continue;
        int qrow = q0w + g * 16 + lr;
        float p[4][4];
        #pragma unroll
        for (int fn = 0; fn < 4; fn++) {
          #pragma unroll
          for (int r = 0; r < 4; r++) {
            float v = s4[g][fn][r];
            if (diag) {
              int s = j0 + fn * 16 + lg * 4 + r;
              v = (s <= qrow) ? v : 0.0f;     // faithful masked_fill(1e-9)
            }
            p[fn][r] = exp2fast(v);
          }
        }
        pa[g][0].u[0] = pkbf(p[0][0], p[0][1]); pa[g][0].u[1] = pkbf(p[0][2], p[0][3]);
        pa[g][0].u[2] = pkbf(p[1][0], p[1][1]); pa[g][0].u[3] = pkbf(p[1][2], p[1][3]);
        pa[g][1].u[0] = pkbf(p[2][0], p[2][1]); pa[g][1].u[1] = pkbf(p[2][2], p[2][3]);
        pa[g][1].u[2] = pkbf(p[3][0], p[3][1]); pa[g][1].u[3] = pkbf(p[3][2], p[3][3]);
        accL[g] = __builtin_amdgcn_mfma_f32_16x16x32_bf16(pa[g][0].s, vone, accL[g], 0, 0, 0);
        accL[g] = __builtin_amdgcn_mfma_f32_16x16x32_bf16(pa[g][1].s, vone, accL[g], 0, 0, 0);
      }
      // PV: V frags loaded once, used by resident groups (slot-matched, swizzled chunks)
      #pragma unroll
      for (int fd = 0; fd < 4; fd++) {
        const u16* vrow = Vl + (fd * 16 + lr) * 64;
        U8 vb0, vb1;
        vb0.s = *(const short8*)(vrow + vc0);   // slots c=0,1
        vb1.s = *(const short8*)(vrow + vc1);   // slots c=2,3
        #pragma unroll
        for (int g = 0; g < 2; g++) {
          if (g >= gcount) continue;
          accO[g][fd] = __builtin_amdgcn_mfma_f32_16x16x32_bf16(pa[g][0].s, vb0.s, accO[g][fd], 0, 0, 0);
          accO[g][fd] = __builtin_amdgcn_mfma_f32_16x16x32_bf16(pa[g][1].s, vb1.s, accO[g][fd], 0, 0, 0);
        }
      }
    }
    __syncthreads();   // drains prefetch vmcnt; guards buffer reuse
  }
  // epilogue: closed-form suffix correction; denominator rows already in accL
  int nmask = T_ - (myJ + 1) * 64;
  const float* sufp = Suf + ((long)bh * (NTILE_ + 1) + (myJ + 1)) * HS_;
  float sufv[4];
  #pragma unroll
  for (int fd = 0; fd < 4; fd++) sufv[fd] = sufp[fd * 16 + lr];
  #pragma unroll
  for (int g = 0; g < 2; g++) {
    if (g >= gcount) continue;
    #pragma unroll
    for (int fd = 0; fd < 4; fd++) {
      #pragma unroll
      for (int r = 0; r < 4; r++) {
        int trow = q0w + g * 16 + lg * 4 + r;
        float o = (accO[g][fd][r] + sufv[fd]) / (accL[g][r] + (float)nmask);
        Mha[((long)(b * T_ + trow)) * D_ + h * HS_ + fd * 16 + lr] = f2bf(o);
      }
    }
  }
}

extern "C" void kernel_launch(void* const* d_in, const int* in_sizes, int n_in,
                              void* d_out, int out_size, void* d_ws, size_t ws_size,
                              hipStream_t stream) {
  const float* x    = (const float*)d_in[0];
  const float* wqkv = (const float*)d_in[1];   // [16][1024][192]
  const float* wout = (const float*)d_in[2];   // [1024][1024]
  float* out = (float*)d_out;

  char* p = (char*)d_ws;
  u16* Xb    = (u16*)p; p += (size_t)M_ * D_ * 2;        // x as bf16 [8192][1024]
  u16* WqkvT = (u16*)p; p += (size_t)NQKV_ * D_ * 2;     // [3072][1024]  (n-major, k-contig)
  u16* WoutT = (u16*)p; p += (size_t)D_ * D_ * 2;        // [1024][1024]  W_out^T
  u16* Qw  = (u16*)p; p += (size_t)B_ * H_ * T_ * HS_ * 2;  // [B,H,T,64], pre-scaled by C^-0.5*log2e
  u16* Kw  = (u16*)p; p += (size_t)B_ * H_ * T_ * HS_ * 2;
  u16* Vw  = (u16*)p; p += (size_t)B_ * H_ * T_ * HS_ * 2;
  u16* Vpw = (u16*)p; p += (size_t)B_ * H_ * T_ * HS_ * 2;  // slot-permuted V tiles
  u16* Mha = (u16*)p; p += (size_t)M_ * D_ * 2;             // [8192][1024]
  float* Suf = (float*)p; p += (size_t)B_ * H_ * (NTILE_ + 1) * HS_ * 4;  // [bh][33][64] fp32
  float* Part = (float*)p; p += (size_t)B_ * H_ * NTILE_ * HS_ * 4;       // [bh][32][64] fp32

  k_cvt_x<<<dim3(M_ * D_ / 8 / 256), dim3(256), 0, stream>>>(x, Xb, M_ * D_ / 8);
  k_transpose_cvt<<<dim3(192 / 32, D_ / 32, H_), dim3(32, 8), 0, stream>>>(
      wqkv, WqkvT, D_, 192, (long)D_ * 192, (long)192 * D_);
  k_transpose_cvt<<<dim3(D_ / 32, D_ / 32, 1), dim3(32, 8), 0, stream>>>(
      wout, WoutT, D_, D_, 0, 0);
  k_gemm<0><<<dim3(M_ / 128, NQKV_ / 128), dim3(256), 0, stream>>>(
      Xb, WqkvT, Qw, Kw, Vw, nullptr, D_);
  k_transpose_v<<<dim3(T_ / 64, 1, B_ * H_), dim3(256), 0, stream>>>(Vw, Vpw, Part);
  k_vscan<<<dim3(B_ * H_), dim3(64), 0, stream>>>(Part, Suf);
  k_attn<<<dim3(B_ * H_, 11), dim3(512), 0, stream>>>(Qw, Kw, Vpw, Suf, Mha);
  k_gemm<1><<<dim3(M_ / 128, D_ / 128), dim3(256), 0, stream>>>(
      Mha, WoutT, nullptr, nullptr, nullptr, out, D_);
}

// Round 20
// 159.065 us; speedup vs baseline: 1.1649x; 1.1649x over previous
//
#include <hip/hip_runtime.h>

typedef unsigned short u16;
typedef __attribute__((ext_vector_type(8))) short short8;   // 8 x bf16 (4 VGPRs)
typedef __attribute__((ext_vector_type(4))) short short4v;
typedef __attribute__((ext_vector_type(4))) float f32x4;

#define B_  4
#define T_  2048
#define D_  1024
#define H_  16
#define HS_ 64
#define M_    (B_ * T_)        /* 8192 */
#define NQKV_ (H_ * 3 * HS_)   /* 3072 */
#define NTILE_ (T_ / 64)       /* 32 */
#define LOG2E_ 1.44269504088896340736f

__device__ __forceinline__ u16 f2bf(float f) {
  union { float f; unsigned u; } v; v.f = f;
  unsigned u = v.u;
  return (u16)((u + 0x7FFFu + ((u >> 16) & 1u)) >> 16);  // RNE
}
__device__ __forceinline__ float bf2f(u16 h) {
  union { unsigned u; float f; } v; v.u = ((unsigned)h) << 16; return v.f;
}
__device__ __forceinline__ unsigned pkbf(float lo, float hi) {
  unsigned r;
  asm("v_cvt_pk_bf16_f32 %0, %1, %2" : "=v"(r) : "v"(lo), "v"(hi));
  return r;
}
__device__ __forceinline__ float exp2fast(float x) {  // scores bounded (|x|<~8): no fixup needed
  float r;
  asm("v_exp_f32 %0, %1" : "=v"(r) : "v"(x));
  return r;
}
__device__ __forceinline__ void gload16(const u16* g, u16* l) {
  __builtin_amdgcn_global_load_lds(
      (const __attribute__((address_space(1))) void*)g,
      (__attribute__((address_space(3))) void*)l, 16, 0, 0);
}

// ---------------- convert x (fp32) -> bf16, 8 elems/thread ----------------
__global__ void k_cvt_x(const float* __restrict__ x, u16* __restrict__ o, int n8) {
  int i = blockIdx.x * 256 + threadIdx.x;
  if (i < n8) {
    float4 v0 = ((const float4*)x)[i * 2];
    float4 v1 = ((const float4*)x)[i * 2 + 1];
    short8 d;
    d[0] = (short)f2bf(v0.x); d[1] = (short)f2bf(v0.y);
    d[2] = (short)f2bf(v0.z); d[3] = (short)f2bf(v0.w);
    d[4] = (short)f2bf(v1.x); d[5] = (short)f2bf(v1.y);
    d[6] = (short)f2bf(v1.z); d[7] = (short)f2bf(v1.w);
    ((short8*)o)[i] = d;
  }
}

// ------- transpose+convert: in fp32 [R][C] (+h*sIn) -> out bf16 [C][R] (+h*sOut) -------
__global__ void k_transpose_cvt(const float* __restrict__ in, u16* __restrict__ out,
                                int R, int C, long sIn, long sOut) {
  __shared__ float tile[32][33];
  int h = blockIdx.z;
  const float* src = in + (long)h * sIn;
  u16* dst = out + (long)h * sOut;
  int r0 = blockIdx.y * 32, c0 = blockIdx.x * 32;
  int tx = threadIdx.x, ty = threadIdx.y;  // 32 x 8
  #pragma unroll
  for (int i = 0; i < 32; i += 8) {
    int r = r0 + ty + i, c = c0 + tx;
    tile[ty + i][tx] = (r < R && c < C) ? src[(long)r * C + c] : 0.f;
  }
  __syncthreads();
  #pragma unroll
  for (int i = 0; i < 32; i += 8) {
    int c = c0 + ty + i, r = r0 + tx;
    if (c < C && r < R) dst[(long)c * R + r] = f2bf(tile[tx][ty + i]);
  }
}

// ---------------- GEMM: C[M][N] = A[M][K] @ Bt[N][K]^T (bf16 in, fp32 acc) ----------------
// r16 proven structure: 2D grid (mt fast; default round-robin pins mt%8 per XCD -> A panels
// L2-resident). Double-buffered issue-before-compute staging: STAGE(t+1 -> buf^1), compute(t)
// [32 MFMA + 16 ds_read of cover], ONE __syncthreads() per K-step.
// BK=64, LDS [128][8 chunks] with chunk^=(row&7) XOR swizzle on BOTH source and reads (786K).
// LDS 64KB; Cs epilogue aliases first 32KB.
// MODE 0: LDS-bounce epilogue -> coalesced 16B stores to Q(*log2e/32), K, V [B,H,T,64] bf16.
// MODE 1: fp32 row-major out (direct stores).
template<int MODE>
__global__ __launch_bounds__(256) void k_gemm(
    const u16* __restrict__ A, const u16* __restrict__ Bt,
    u16* __restrict__ Oq, u16* __restrict__ Ok, u16* __restrict__ Ov,
    float* __restrict__ Of, int K) {
  __shared__ __align__(16) u16 smem[32768];   // [buf]*16384: As 8192 | Bs 8192 ; Cs aliases
  int mt = blockIdx.x, nt = blockIdx.y;
  int tid = threadIdx.x;
  int wid = tid >> 6, lane = tid & 63;
  int lr = lane & 15, lg = lane >> 4;
  int mw = (wid >> 1) * 64, nw = (wid & 1) * 64;
  // staging: 1024 chunks/matrix/K-step, 4 loads/thread; LDS slot (row,q) <- G[row][q ^ (row&7)]
  const u16* srcA[4]; const u16* srcB[4];
  int dstOff[4];
  #pragma unroll
  for (int l = 0; l < 4; l++) {
    int c = l * 256 + wid * 64 + lane;
    int r = c >> 3, q = c & 7;
    int qs = q ^ (r & 7);
    srcA[l] = A  + (long)(mt * 128 + r) * K + qs * 8;
    srcB[l] = Bt + (long)(nt * 128 + r) * K + qs * 8;
    dstOff[l] = (l * 256 + wid * 64) * 8;     // wave-uniform base (lane*16B implicit)
  }
  const int rsw = (lr & 7);                   // row&7 for all frag rows (row ≡ lr mod 16)
  f32x4 acc[4][4] = {};
  const int nIter = K / 64;

#define STAGE_G(bb, k0) do {                       \
    u16* ab_ = smem + (bb) * 16384;                \
    gload16(srcA[0] + (k0), ab_ + dstOff[0]);      \
    gload16(srcA[1] + (k0), ab_ + dstOff[1]);      \
    gload16(srcA[2] + (k0), ab_ + dstOff[2]);      \
    gload16(srcA[3] + (k0), ab_ + dstOff[3]);      \
    u16* bb_ = ab_ + 8192;                         \
    gload16(srcB[0] + (k0), bb_ + dstOff[0]);      \
    gload16(srcB[1] + (k0), bb_ + dstOff[1]);      \
    gload16(srcB[2] + (k0), bb_ + dstOff[2]);      \
    gload16(srcB[3] + (k0), bb_ + dstOff[3]); } while (0)

  STAGE_G(0, 0);
  __syncthreads();
  for (int t = 0; t < nIter; t++) {
    int cur = t & 1;
    if (t + 1 < nIter) STAGE_G(cur ^ 1, (t + 1) * 64);   // prefetch hidden under compute
    const u16* As = smem + cur * 16384;
    const u16* Bs = As + 8192;
    #pragma unroll
    for (int kk = 0; kk < 2; kk++) {
      const int fc = ((kk * 4 + lg) ^ rsw) << 3;
      short8 af[4], bf[4];
      #pragma unroll
      for (int i = 0; i < 4; i++)
        af[i] = *(const short8*)(As + (mw + i * 16 + lr) * 64 + fc);
      #pragma unroll
      for (int i = 0; i < 4; i++)
        bf[i] = *(const short8*)(Bs + (nw + i * 16 + lr) * 64 + fc);
      #pragma unroll
      for (int i = 0; i < 4; i++)
        #pragma unroll
        for (int j = 0; j < 4; j++)
          acc[i][j] = __builtin_amdgcn_mfma_f32_16x16x32_bf16(af[i], bf[j], acc[i][j], 0, 0, 0);
    }
    __syncthreads();   // drains prefetch vmcnt (covered by compute); guards buffer reuse
  }
#undef STAGE_G

  if constexpr (MODE == 0) {
    // bounce through LDS (Cs aliases smem), then coalesced 16B stores
    u16* Cs = smem;
    #pragma unroll
    for (int j = 0; j < 4; j++) {
      int fbase = (nt * 128 + nw + j * 16) % 192;          // wave-uniform, multiple of 16
      float sc = (fbase < 64) ? (0.03125f * LOG2E_) : 1.0f;  // Q gets C^-0.5 * log2e
      #pragma unroll
      for (int i = 0; i < 4; i++) {
        int row = mw + i * 16 + lg * 4;
        int col = nw + j * 16 + lr;
        #pragma unroll
        for (int r = 0; r < 4; r++)
          Cs[(row + r) * 128 + col] = f2bf(acc[i][j][r] * sc);
      }
    }
    __syncthreads();
    #pragma unroll
    for (int p5 = 0; p5 < 8; p5++) {
      int idx = p5 * 2048 + tid * 8;
      int row = idx >> 7, col = idx & 127;
      short8 v = *(const short8*)(Cs + row * 128 + col);
      int m = mt * 128 + row;
      int n0 = nt * 128 + col;
      int b = m >> 11, t = m & (T_ - 1);
      int h = n0 / 192, f = n0 % 192;
      long o = (((long)(b * H_ + h)) * T_ + t) * HS_;
      u16* dst = (f < 64) ? (Oq + o + f) : (f < 128) ? (Ok + o + f - 64) : (Ov + o + f - 128);
      *(short8*)dst = v;
    }
  } else {
    #pragma unroll
    for (int i = 0; i < 4; i++) {
      #pragma unroll
      for (int j = 0; j < 4; j++) {
        int mbase = mt * 128 + mw + i * 16 + lg * 4;
        int n     = nt * 128 + nw + j * 16 + lr;
        #pragma unroll
        for (int r = 0; r < 4; r++)
          Of[(long)(mbase + r) * D_ + n] = acc[i][j][r];
      }
    }
  }
}

// -------- V [bh][T][64] -> slot-permuted tiles Vp[bh][jt][d][pos] + per-tile column sums --------
// pos(s) within a 64-tile: s = 16c + 4lg + r  ->  pos = lg*16 + c*4 + r
__global__ void k_transpose_v(const u16* __restrict__ V, u16* __restrict__ Vp,
                              float* __restrict__ Partial) {
  __shared__ u16 tile[64][65];
  __shared__ float psum[4][64];
  int bh = blockIdx.z;
  int jt = blockIdx.x;          // tile index
  int t0 = jt * 64;
  int tx = threadIdx.x & 63, ty = threadIdx.x >> 6;
  const u16* src = V + (long)bh * T_ * HS_;
  u16* dtile = Vp + (((long)bh * NTILE_) + jt) * 64 * 64;
  #pragma unroll
  for (int i = 0; i < 64; i += 4)
    tile[ty + i][tx] = src[(long)(t0 + ty + i) * HS_ + tx];
  __syncthreads();
  int pos = ((tx >> 2) & 3) * 16 + ((tx >> 4) & 3) * 4 + (tx & 3);
  #pragma unroll
  for (int i = 0; i < 64; i += 4)
    dtile[(ty + i) * 64 + pos] = tile[tx][ty + i];
  // per-tile column sums: thread (ty,tx) sums 16 rows of dim tx
  float s = 0.f;
  #pragma unroll
  for (int i = 0; i < 16; i++)
    s += bf2f(tile[ty * 16 + i][tx]);
  psum[ty][tx] = s;
  __syncthreads();
  if (threadIdx.x < 64)
    Partial[((long)bh * NTILE_ + jt) * HS_ + threadIdx.x] =
        psum[0][threadIdx.x] + psum[1][threadIdx.x] + psum[2][threadIdx.x] + psum[3][threadIdx.x];
}

// -------- suffix scan over tile sums: Suf[bh][j][d] = sum_{jt >= j} Partial[bh][jt][d] --------
__global__ void k_vscan(const float* __restrict__ Partial, float* __restrict__ Suf) {
  int bh = blockIdx.x;
  int d = threadIdx.x;
  const float* Pb = Partial + (long)bh * NTILE_ * HS_;
  float* Sb = Suf + (long)bh * (NTILE_ + 1) * HS_;
  float acc = 0.f;
  Sb[NTILE_ * HS_ + d] = 0.f;
  for (int j = NTILE_ - 1; j >= 0; j--) {
    acc += Pb[j * HS_ + d];
    Sb[j * HS_ + d] = acc;
  }
}

// ---------------- fused attention: 256 q/block (8 waves), dbuf gload_lds prefetch ----------------
// UN-PAIRED: each block handles ONE 256-row supertile; grid 512 -> 2 blocks/CU = 16 waves/CU.
// Heavy-first dispatch (st = 7 - blockIdx.y) so long blocks start first; light blocks backfill.
// One barrier per k-tile. Denominator via ones-MFMA; exp2 via raw v_exp_f32; XOR swizzle on
// staging source + LDS reads. Wave w diag tile = 4st + (w>>1); masked suffix via closed form.
__global__ __launch_bounds__(512, 2) void k_attn(
    const u16* __restrict__ Q, const u16* __restrict__ Kc,
    const u16* __restrict__ Vp, const float* __restrict__ Suf,
    u16* __restrict__ Mha) {
  __shared__ __align__(16) u16 Ks[2][64 * 64];
  __shared__ __align__(16) u16 Vs[2][64 * 64];
  int bh = blockIdx.x;
  int st = 7 - (int)blockIdx.y;             // heavy supertiles dispatch first
  int b = bh >> 4, h = bh & 15;
  int tid = threadIdx.x, wid = tid >> 6, lane = tid & 63;
  int lr = lane & 15, lg = lane >> 4;
  const u16* Qb = Q  + (long)bh * T_ * HS_;
  const u16* Kb = Kc + (long)bh * T_ * HS_;
  const u16* Vb = Vp + (long)bh * T_ * HS_;   // [32 tiles][64 d][64 pos]
  union U8 { unsigned u[4]; short8 s; };
  const short8 vone = { (short)0x3F80, (short)0x3F80, (short)0x3F80, (short)0x3F80,
                        (short)0x3F80, (short)0x3F80, (short)0x3F80, (short)0x3F80 };
  // staging source (per-lane, inverse-swizzled 16B chunk), tile-relative; 512 chunks = 512 thr
  int srow = tid >> 3;                          // 0..63
  int schunk = (tid & 7) ^ (srow & 7);
  const u16* kSrc = Kb + srow * 64 + schunk * 8;
  const u16* vSrc = Vb + srow * 64 + schunk * 8;
  const int r7 = lr & 7;                        // row&7 for all frag rows (row ≡ lr mod 16)
  const int kc0 = (lg ^ r7) << 3, kc1 = ((4 + lg) ^ r7) << 3;
  const int vc0 = ((2 * lg) ^ r7) << 3, vc1 = ((2 * lg + 1) ^ r7) << 3;

  int q0w = st * 256 + wid * 32;            // wave's first q row
  short8 qf[2][2];
  #pragma unroll
  for (int g = 0; g < 2; g++) {
    const u16* qp = Qb + (long)(q0w + g * 16 + lr) * HS_;
    qf[g][0] = *(const short8*)(qp + lg * 8);
    qf[g][1] = *(const short8*)(qp + 32 + lg * 8);
  }
  f32x4 accO[2][4] = {};                    // [group][fd]; O[q=lg*4+r][d=fd*16+lr]
  f32x4 accL[2] = {};                       // denominator rows (ones-MFMA)
  const int blkJ = 4 * st + 3;              // last tile staged by the block
  const int myJ  = 4 * st + (wid >> 1);     // this wave's diag tile
  // prologue: stage tile 0 into buf 0 (1 K-chunk + 1 V-chunk per thread)
  gload16(kSrc, &Ks[0][wid * 512]);
  gload16(vSrc, &Vs[0][wid * 512]);
  __syncthreads();
  for (int jt = 0; jt <= blkJ; jt++) {
    int cur = jt & 1;
    if (jt < blkJ) {           // prefetch next tile into other buffer
      long off = (long)(jt + 1) * 4096;
      gload16(kSrc + off, &Ks[cur ^ 1][wid * 512]);
      gload16(vSrc + off, &Vs[cur ^ 1][wid * 512]);
    }
    if (jt <= myJ) {
      int j0 = jt * 64;
      const bool diag = (jt == myJ);
      const u16* Kl = Ks[cur];
      const u16* Vl = Vs[cur];
      // S^T = K Q^T : lane holds S[q=lr][s = j0 + fn*16 + lg*4 + r] per group
      f32x4 s4[2][4];
      #pragma unroll
      for (int fn = 0; fn < 4; fn++) {
        const u16* krow = Kl + (fn * 16 + lr) * 64;
        short8 kb0 = *(const short8*)(krow + kc0);
        short8 kb1 = *(const short8*)(krow + kc1);
        #pragma unroll
        for (int g = 0; g < 2; g++) {
          f32x4 z = {};
          z = __builtin_amdgcn_mfma_f32_16x16x32_bf16(kb0, qf[g][0], z, 0, 0, 0);
          z = __builtin_amdgcn_mfma_f32_16x16x32_bf16(kb1, qf[g][1], z, 0, 0, 0);
          s4[g][fn] = z;
        }
      }
      // no-max softmax + pack; denominator via ones-MFMA (lands in accO row layout)
      U8 pa[2][2];
      #pragma unroll
      for (int g = 0; g < 2; g++) {
        int qrow = q0w + g * 16 + lr;
        float p[4][4];
        #pragma unroll
        for (int fn = 0; fn < 4; fn++) {
          #pragma unroll
          for (int r = 0; r < 4; r++) {
            float v = s4[g][fn][r];
            if (diag) {
              int s = j0 + fn * 16 + lg * 4 + r;
              v = (s <= qrow) ? v : 0.0f;     // faithful masked_fill(1e-9)
            }
            p[fn][r] = exp2fast(v);
          }
        }
        pa[g][0].u[0] = pkbf(p[0][0], p[0][1]); pa[g][0].u[1] = pkbf(p[0][2], p[0][3]);
        pa[g][0].u[2] = pkbf(p[1][0], p[1][1]); pa[g][0].u[3] = pkbf(p[1][2], p[1][3]);
        pa[g][1].u[0] = pkbf(p[2][0], p[2][1]); pa[g][1].u[1] = pkbf(p[2][2], p[2][3]);
        pa[g][1].u[2] = pkbf(p[3][0], p[3][1]); pa[g][1].u[3] = pkbf(p[3][2], p[3][3]);
        accL[g] = __builtin_amdgcn_mfma_f32_16x16x32_bf16(pa[g][0].s, vone, accL[g], 0, 0, 0);
        accL[g] = __builtin_amdgcn_mfma_f32_16x16x32_bf16(pa[g][1].s, vone, accL[g], 0, 0, 0);
      }
      // PV: V frags loaded once, used by both groups (slot-matched, swizzled chunks)
      #pragma unroll
      for (int fd = 0; fd < 4; fd++) {
        const u16* vrow = Vl + (fd * 16 + lr) * 64;
        U8 vb0, vb1;
        vb0.s = *(const short8*)(vrow + vc0);   // slots c=0,1
        vb1.s = *(const short8*)(vrow + vc1);   // slots c=2,3
        #pragma unroll
        for (int g = 0; g < 2; g++) {
          accO[g][fd] = __builtin_amdgcn_mfma_f32_16x16x32_bf16(pa[g][0].s, vb0.s, accO[g][fd], 0, 0, 0);
          accO[g][fd] = __builtin_amdgcn_mfma_f32_16x16x32_bf16(pa[g][1].s, vb1.s, accO[g][fd], 0, 0, 0);
        }
      }
    }
    __syncthreads();   // drains prefetch vmcnt; guards buffer reuse
  }
  // epilogue: closed-form suffix correction; denominator rows already in accL
  int nmask = T_ - (myJ + 1) * 64;
  const float* sufp = Suf + ((long)bh * (NTILE_ + 1) + (myJ + 1)) * HS_;
  float sufv[4];
  #pragma unroll
  for (int fd = 0; fd < 4; fd++) sufv[fd] = sufp[fd * 16 + lr];
  #pragma unroll
  for (int g = 0; g < 2; g++) {
    #pragma unroll
    for (int fd = 0; fd < 4; fd++) {
      #pragma unroll
      for (int r = 0; r < 4; r++) {
        int trow = q0w + g * 16 + lg * 4 + r;
        float o = (accO[g][fd][r] + sufv[fd]) / (accL[g][r] + (float)nmask);
        Mha[((long)(b * T_ + trow)) * D_ + h * HS_ + fd * 16 + lr] = f2bf(o);
      }
    }
  }
}

extern "C" void kernel_launch(void* const* d_in, const int* in_sizes, int n_in,
                              void* d_out, int out_size, void* d_ws, size_t ws_size,
                              hipStream_t stream) {
  const float* x    = (const float*)d_in[0];
  const float* wqkv = (const float*)d_in[1];   // [16][1024][192]
  const float* wout = (const float*)d_in[2];   // [1024][1024]
  float* out = (float*)d_out;

  char* p = (char*)d_ws;
  u16* Xb    = (u16*)p; p += (size_t)M_ * D_ * 2;        // x as bf16 [8192][1024]
  u16* WqkvT = (u16*)p; p += (size_t)NQKV_ * D_ * 2;     // [3072][1024]  (n-major, k-contig)
  u16* WoutT = (u16*)p; p += (size_t)D_ * D_ * 2;        // [1024][1024]  W_out^T
  u16* Qw  = (u16*)p; p += (size_t)B_ * H_ * T_ * HS_ * 2;  // [B,H,T,64], pre-scaled by C^-0.5*log2e
  u16* Kw  = (u16*)p; p += (size_t)B_ * H_ * T_ * HS_ * 2;
  u16* Vw  = (u16*)p; p += (size_t)B_ * H_ * T_ * HS_ * 2;
  u16* Vpw = (u16*)p; p += (size_t)B_ * H_ * T_ * HS_ * 2;  // slot-permuted V tiles
  u16* Mha = (u16*)p; p += (size_t)M_ * D_ * 2;             // [8192][1024]
  float* Suf = (float*)p; p += (size_t)B_ * H_ * (NTILE_ + 1) * HS_ * 4;  // [bh][33][64] fp32
  float* Part = (float*)p; p += (size_t)B_ * H_ * NTILE_ * HS_ * 4;       // [bh][32][64] fp32

  k_cvt_x<<<dim3(M_ * D_ / 8 / 256), dim3(256), 0, stream>>>(x, Xb, M_ * D_ / 8);
  k_transpose_cvt<<<dim3(192 / 32, D_ / 32, H_), dim3(32, 8), 0, stream>>>(
      wqkv, WqkvT, D_, 192, (long)D_ * 192, (long)192 * D_);
  k_transpose_cvt<<<dim3(D_ / 32, D_ / 32, 1), dim3(32, 8), 0, stream>>>(
      wout, WoutT, D_, D_, 0, 0);
  k_gemm<0><<<dim3(M_ / 128, NQKV_ / 128), dim3(256), 0, stream>>>(
      Xb, WqkvT, Qw, Kw, Vw, nullptr, D_);
  k_transpose_v<<<dim3(T_ / 64, 1, B_ * H_), dim3(256), 0, stream>>>(Vw, Vpw, Part);
  k_vscan<<<dim3(B_ * H_), dim3(64), 0, stream>>>(Part, Suf);
  k_attn<<<dim3(B_ * H_, 8), dim3(512), 0, stream>>>(Qw, Kw, Vpw, Suf, Mha);
  k_gemm<1><<<dim3(M_ / 128, D_ / 128), dim3(256), 0, stream>>>(
      Mha, WoutT, nullptr, nullptr, nullptr, out, D_);
}